// Round 5
// baseline (549.471 us; speedup 1.0000x reference)
//
#include <hip/hip_runtime.h>
#include <hip/hip_bf16.h>

#define DD 32   // node/output dim
#define HH 64   // psi hidden
// PSI_IN = 5*32 = 160

typedef __attribute__((ext_vector_type(8))) short bf16x8;   // 8 bf16 = 4 VGPRs
typedef __attribute__((ext_vector_type(4))) float f32x4;
typedef __attribute__((ext_vector_type(4))) unsigned int u32x4;
typedef __attribute__((ext_vector_type(4))) unsigned short us16x4;

static __device__ __forceinline__ unsigned short f2bf(float x) {
    union { float f; unsigned u; } v; v.f = x;
    return (unsigned short)((v.u + 0x7FFFu + ((v.u >> 16) & 1u)) >> 16);
}
static __device__ __forceinline__ float bf2f(unsigned short h) {
    union { unsigned u; float f; } v; v.u = ((unsigned)h) << 16; return v.f;
}
// packed f32x2 -> bf16x2 (v_cvt_pk_bf16_f32), low = a
static __device__ __forceinline__ unsigned pk2(float a, float b) {
    __hip_bfloat162 h = __float22bfloat162_rn(make_float2(a, b));
    union { __hip_bfloat162 h2; unsigned u; } cv; cv.h2 = h; return cv.u;
}

// 34 A-operand weight fragments (transposed MLP: M = out-features).
// 16x16x32 A-frag: lane l (c=l&15, q=l>>4): m = t*16+c, k-slot = q*8+j.
//  f 0..19  wf0 (t=f/5, kk=f%5):  k = kk*32 + q*8 + j                 <- w0[k][m]
//  f 20..27 wf1 (t,kp):           k = kp*32 + (j>>2)*16 + q*4 + (j&3) <- w1[k][m]
//  f 28..31 wf2 (t,kp):           same interleave                     <- w2[k][m]
//  f 32..33 wfW (t):              k = (j>>2)*16 + q*4 + (j&3)         <- W[k][m]
// (interleave = dual-16K trick so layer-i C-layout IS layer-(i+1)'s B-frag)
__global__ __launch_bounds__(256) void prep_weights(
    const float* __restrict__ w0, const float* __restrict__ w1,
    const float* __restrict__ w2, const float* __restrict__ W,
    unsigned short* __restrict__ frags)
{
    const int tid = blockIdx.x * 256 + threadIdx.x;
    const int f = tid >> 6, l = tid & 63;
    if (f >= 34) return;
    const int c = l & 15, q = l >> 4;
    unsigned short* dst = frags + f * 512 + l * 8;
    if (f < 20) {
        const int t = f / 5, kk = f % 5, m = t * 16 + c;
        #pragma unroll
        for (int j = 0; j < 8; ++j)
            dst[j] = f2bf(w0[(kk * 32 + q * 8 + j) * HH + m]);
    } else if (f < 28) {
        const int f1 = f - 20, t = f1 >> 1, kp = f1 & 1, m = t * 16 + c;
        #pragma unroll
        for (int j = 0; j < 8; ++j)
            dst[j] = f2bf(w1[(kp * 32 + (j >> 2) * 16 + q * 4 + (j & 3)) * HH + m]);
    } else if (f < 32) {
        const int f2i = f - 28, t = f2i >> 1, kp = f2i & 1, m = t * 16 + c;
        #pragma unroll
        for (int j = 0; j < 8; ++j)
            dst[j] = f2bf(w2[(kp * 32 + (j >> 2) * 16 + q * 4 + (j & 3)) * DD + m]);
    } else {
        const int t = f - 32, m = t * 16 + c;
        #pragma unroll
        for (int j = 0; j < 8; ++j)
            dst[j] = f2bf(W[((j >> 2) * 16 + q * 4 + (j & 3)) * DD + m]);
    }
}

// Pack node tables to bf16: nt[n] = [h_s[n][0..31] | h_d[n][0..31]], one 128-B
// block per node -> per-edge gather traffic halves and both tables share a line.
__global__ __launch_bounds__(256) void prep_nodes(
    const float* __restrict__ h_d, const float* __restrict__ h_s,
    unsigned short* __restrict__ nt, int ND)
{
    const int idx = blockIdx.x * 256 + threadIdx.x;   // over N*32
    if (idx >= ND) return;
    const int n = idx >> 5, d = idx & 31;
    nt[(size_t)n * 64 + d]      = f2bf(h_s[idx]);
    nt[(size_t)n * 64 + 32 + d] = f2bf(h_d[idx]);
}

// One wave per 16-edge tile. Transposed MLP (features on M, edges on N),
// zero inter-layer LDS, fused @W, atomics into out (pre-filled with h_d_prev).
// Node gathers from bf16-packed nt; weights staged in LDS (32 KB/block).
// Epilogue transposes through per-wave bf16 scratch -> coalesced atomics.
__global__ __launch_bounds__(512, 4) void edge_mfma(
    const unsigned short* __restrict__ nt,
    const float* __restrict__ ef,
    const int* __restrict__ snd, const int* __restrict__ rcv,
    const unsigned short* __restrict__ frags,
    const float* __restrict__ b0, const float* __restrict__ b1,
    const float* __restrict__ b2,
    float* __restrict__ out, int E, int ntiles)
{
    __shared__ __align__(16) unsigned short wlds[32 * 512];   // 32 KB weight frags
    __shared__ __align__(16) unsigned short sbuf[8][16 * 40]; // 10 KB transpose scratch

    const int tid = threadIdx.x;
    const int lane = tid & 63, w = tid >> 6;
    const int c = lane & 15, q = lane >> 4;

    // stage wf0+wf1+wf2 -> LDS (2048 u32x4 / 512 threads = 4 iters)
    {
        const u32x4* src = (const u32x4*)frags;
        u32x4* dst = (u32x4*)wlds;
        #pragma unroll
        for (int i = 0; i < 4; ++i) dst[tid + i * 512] = src[tid + i * 512];
    }
    // wfW -> registers
    const bf16x8 wfW0 = *(const bf16x8*)(frags + 32 * 512 + lane * 8);
    const bf16x8 wfW1 = *(const bf16x8*)(frags + 33 * 512 + lane * 8);
    __syncthreads();

    // bias fragments: feature = t*16 + q*4 + r
    f32x4 b0v[4], b1v[4], b2v[2];
    #pragma unroll
    for (int t = 0; t < 4; ++t) b0v[t] = *(const f32x4*)(b0 + t * 16 + q * 4);
    #pragma unroll
    for (int t = 0; t < 4; ++t) b1v[t] = *(const f32x4*)(b1 + t * 16 + q * 4);
    #pragma unroll
    for (int t = 0; t < 2; ++t) b2v[t] = *(const f32x4*)(b2 + t * 16 + q * 4);

    unsigned short* sw = sbuf[w];
    const int nw = gridDim.x * 8;
    int tile = blockIdx.x * 8 + w;
    if (tile >= ntiles) return;

    int e0 = tile * 16 + c; if (e0 >= E) e0 = E - 1;
    int si = snd[e0], ri = rcv[e0];

    while (true) {
        const int base = tile * 16;
        int ec = base + c; if (ec >= E) ec = E - 1;

        const unsigned short* bsi = nt + (size_t)si * 64;
        const unsigned short* bri = nt + (size_t)ri * 64;

        // gathers (issued up front): 4 bf16 chunks + ef fp32 + bf16 diffs
        bf16x8 gs0 = *(const bf16x8*)(bsi + q * 8);          // h_s[si]
        bf16x8 gs1 = *(const bf16x8*)(bri + q * 8);          // h_s[ri]
        bf16x8 gs2 = *(const bf16x8*)(bsi + 32 + q * 8);     // h_d[si]
        bf16x8 gs3 = *(const bf16x8*)(bri + 32 + q * 8);     // h_d[ri]
        const float* s4 = ef + (size_t)ec * DD;
        const f32x4 e0v = *(const f32x4*)(s4 + q * 8);
        const f32x4 e1v = *(const f32x4*)(s4 + q * 8 + 4);
        us16x4 dif[2], djf[2];
        #pragma unroll
        for (int t = 0; t < 2; ++t) {
            dif[t] = *(const us16x4*)(bsi + 32 + t * 16 + q * 4);
            djf[t] = *(const us16x4*)(bri + 32 + t * 16 + q * 4);
        }

        // prefetch next tile's indices
        const int ntile = tile + nw;
        int nsi = si, nri = ri;
        if (ntile < ntiles) {
            int en = ntile * 16 + c; if (en >= E) en = E - 1;
            nsi = snd[en]; nri = rcv[en];
        }

        // ---- layer 0: X1^T = W0^T @ X0^T, B-frags direct from bf16 gathers ----
        f32x4 c0[4] = {b0v[0], b0v[1], b0v[2], b0v[3]};
        bf16x8 bch[5];
        bch[0] = gs0; bch[1] = gs1; bch[2] = gs2; bch[3] = gs3;
        {
            union { unsigned u[4]; bf16x8 v; } bb;
            bb.u[0] = pk2(e0v[0], e0v[1]); bb.u[1] = pk2(e0v[2], e0v[3]);
            bb.u[2] = pk2(e1v[0], e1v[1]); bb.u[3] = pk2(e1v[2], e1v[3]);
            bch[4] = bb.v;
        }
        #pragma unroll
        for (int kk = 0; kk < 5; ++kk) {
            #pragma unroll
            for (int t = 0; t < 4; ++t) {
                const bf16x8 a = *(const bf16x8*)(wlds + (t * 5 + kk) * 512 + lane * 8);
                c0[t] = __builtin_amdgcn_mfma_f32_16x16x32_bf16(a, bch[kk], c0[t], 0, 0, 0);
            }
        }
        unsigned x1[4][2];
        #pragma unroll
        for (int kt = 0; kt < 4; ++kt) {
            x1[kt][0] = pk2(fmaxf(c0[kt][0], 0.f), fmaxf(c0[kt][1], 0.f));
            x1[kt][1] = pk2(fmaxf(c0[kt][2], 0.f), fmaxf(c0[kt][3], 0.f));
        }

        // ---- layer 1 (dual-16K MFMAs) ----
        f32x4 c1[4] = {b1v[0], b1v[1], b1v[2], b1v[3]};
        #pragma unroll
        for (int kp = 0; kp < 2; ++kp) {
            union { unsigned u[4]; bf16x8 v; } bb;
            bb.u[0] = x1[2 * kp][0];     bb.u[1] = x1[2 * kp][1];
            bb.u[2] = x1[2 * kp + 1][0]; bb.u[3] = x1[2 * kp + 1][1];
            #pragma unroll
            for (int t = 0; t < 4; ++t) {
                const bf16x8 a = *(const bf16x8*)(wlds + (20 + t * 2 + kp) * 512 + lane * 8);
                c1[t] = __builtin_amdgcn_mfma_f32_16x16x32_bf16(a, bb.v, c1[t], 0, 0, 0);
            }
        }
        unsigned x2[4][2];
        #pragma unroll
        for (int kt = 0; kt < 4; ++kt) {
            x2[kt][0] = pk2(fmaxf(c1[kt][0], 0.f), fmaxf(c1[kt][1], 0.f));
            x2[kt][1] = pk2(fmaxf(c1[kt][2], 0.f), fmaxf(c1[kt][3], 0.f));
        }

        // ---- layer 2 ----
        f32x4 c2[2] = {b2v[0], b2v[1]};
        #pragma unroll
        for (int kp = 0; kp < 2; ++kp) {
            union { unsigned u[4]; bf16x8 v; } bb;
            bb.u[0] = x2[2 * kp][0];     bb.u[1] = x2[2 * kp][1];
            bb.u[2] = x2[2 * kp + 1][0]; bb.u[3] = x2[2 * kp + 1][1];
            #pragma unroll
            for (int t = 0; t < 2; ++t) {
                const bf16x8 a = *(const bf16x8*)(wlds + (28 + t * 2 + kp) * 512 + lane * 8);
                c2[t] = __builtin_amdgcn_mfma_f32_16x16x32_bf16(a, bb.v, c2[t], 0, 0, 0);
            }
        }

        // ---- s_ij = relu(psi) * (h_dj - h_di)  [bf16 diffs], then fused @W ----
        union { unsigned u[4]; bf16x8 v; } sb;
        #pragma unroll
        for (int t = 0; t < 2; ++t) {
            const float v0 = fmaxf(c2[t][0], 0.f) * (bf2f(djf[t].x) - bf2f(dif[t].x));
            const float v1 = fmaxf(c2[t][1], 0.f) * (bf2f(djf[t].y) - bf2f(dif[t].y));
            const float v2 = fmaxf(c2[t][2], 0.f) * (bf2f(djf[t].z) - bf2f(dif[t].z));
            const float v3 = fmaxf(c2[t][3], 0.f) * (bf2f(djf[t].w) - bf2f(dif[t].w));
            sb.u[2 * t]     = pk2(v0, v1);
            sb.u[2 * t + 1] = pk2(v2, v3);
        }
        const f32x4 zero = {0.f, 0.f, 0.f, 0.f};
        f32x4 c3[2];
        c3[0] = __builtin_amdgcn_mfma_f32_16x16x32_bf16(wfW0, sb.v, zero, 0, 0, 0);
        c3[1] = __builtin_amdgcn_mfma_f32_16x16x32_bf16(wfW1, sb.v, zero, 0, 0, 0);

        // ---- transpose via per-wave bf16 scratch, then coalesced atomics ----
        #pragma unroll
        for (int t = 0; t < 2; ++t) {
            uint2 pv;
            pv.x = pk2(c3[t][0], c3[t][1]);
            pv.y = pk2(c3[t][2], c3[t][3]);
            *(uint2*)(sw + c * 40 + t * 16 + q * 4) = pv;
        }
        #pragma unroll
        for (int r = 0; r < 4; ++r) {
            const int er = base + q * 4 + r;
            if (er < E) {
                const int rr = rcv[er];
                const float v0 = bf2f(sw[(q * 4 + r) * 40 + c]);
                const float v1 = bf2f(sw[(q * 4 + r) * 40 + 16 + c]);
                atomicAdd(out + (size_t)rr * DD + c, v0);
                atomicAdd(out + (size_t)rr * DD + 16 + c, v1);
            }
        }

        if (ntile >= ntiles) break;
        tile = ntile; si = nsi; ri = nri;
    }
}

extern "C" void kernel_launch(void* const* d_in, const int* in_sizes, int n_in,
                              void* d_out, int out_size, void* d_ws, size_t ws_size,
                              hipStream_t stream) {
    const float* h_d = (const float*)d_in[0];
    const float* h_s = (const float*)d_in[1];
    const float* ef  = (const float*)d_in[2];
    const int*   snd = (const int*)d_in[3];
    const int*   rcv = (const int*)d_in[4];
    const float* w0  = (const float*)d_in[5];
    const float* b0  = (const float*)d_in[6];
    const float* w1  = (const float*)d_in[7];
    const float* b1  = (const float*)d_in[8];
    const float* w2  = (const float*)d_in[9];
    const float* b2  = (const float*)d_in[10];
    const float* W   = (const float*)d_in[11];
    float* out = (float*)d_out;

    const int N = in_sizes[0] / DD;
    const int E = in_sizes[3];
    const int ntiles = (E + 15) / 16;

    // d_ws: frags (34*512 shorts = 34 KB, 128-B aligned) then nt (N*64 shorts)
    unsigned short* frags = (unsigned short*)d_ws;
    unsigned short* nt = frags + 34 * 512;

    hipMemcpyAsync(out, h_d, (size_t)N * DD * sizeof(float),
                   hipMemcpyDeviceToDevice, stream);
    prep_weights<<<9, 256, 0, stream>>>(w0, w1, w2, W, frags);
    prep_nodes<<<(N * DD + 255) / 256, 256, 0, stream>>>(h_d, h_s, nt, N * DD);
    edge_mfma<<<768, 512, 0, stream>>>(nt, ef, snd, rcv, frags,
                                       b0, b1, b2, out, E, ntiles);
}